// Round 9
// baseline (918.854 us; speedup 1.0000x reference)
//
#include <hip/hip_runtime.h>
#include <hip/hip_bf16.h>
#include <cstdint>

#define NEG_SLOPE 0.2f

typedef __attribute__((ext_vector_type(8))) short bf16x8;
typedef __attribute__((ext_vector_type(4))) float f32x4;
typedef unsigned short u16;

// ---------- bf16 helpers ----------
__device__ __forceinline__ u16 f2bf(float f) {              // RNE
    unsigned u = __float_as_uint(f);
    return (u16)((u + 0x7FFFu + ((u >> 16) & 1u)) >> 16);
}
__device__ __forceinline__ float bf2f(u16 h) {
    return __uint_as_float(((unsigned)h) << 16);
}
__device__ __forceinline__ void splitbf(float v, u16& hi, u16& lo) {
    hi = f2bf(v);
    lo = f2bf(v - bf2f(hi));
}
// trunc-hi split of 8 floats -> hi/lo bf16x8 (cheap, used in gemm1 frag read)
__device__ __forceinline__ void split8(float4 a, float4 b, bf16x8& h, bf16x8& l) {
    float f[8] = {a.x, a.y, a.z, a.w, b.x, b.y, b.z, b.w};
    #pragma unroll
    for (int i = 0; i < 8; ++i) {
        unsigned u = __float_as_uint(f[i]);
        h[i] = (short)(u >> 16);                            // truncated hi
        float rf = f[i] - __uint_as_float(u & 0xFFFF0000u); // exact remainder
        l[i] = (short)f2bf(rf);
    }
}

// ---------- async global->LDS (fire-and-forget, no VGPR round trip) ----------
__device__ __forceinline__ void gl_lds4(const void* g, void* l) {
    __builtin_amdgcn_global_load_lds(
        (const __attribute__((address_space(1))) void*)g,
        (__attribute__((address_space(3))) void*)l, 4, 0, 0);
}
__device__ __forceinline__ void gl_lds16(const void* g, void* l) {
    __builtin_amdgcn_global_load_lds(
        (const __attribute__((address_space(1))) void*)g,
        (__attribute__((address_space(3))) void*)l, 16, 0, 0);
}

// ---------- tiled bf16 plane address: 4096-elem [128 x 32] tile, swizzled LDS image ----------
__device__ __forceinline__ size_t tAddr(int r, int k, int blk, int nkt) {
    int kt = k >> 5, cc = (k >> 3) & 3, ci = k & 7;
    int ch = cc ^ ((r >> 1) & 3);
    return (((size_t)blk * nkt + kt) << 12) + ((size_t)r << 5) + (ch << 3) + ci;
}

// ---------- weight prep: W [K][M] fp32 -> tiled hi/lo bf16 images ----------
__global__ __launch_bounds__(256) void convertB(
    const float* __restrict__ W, u16* __restrict__ bth, u16* __restrict__ btl,
    int K, int M, int Kp)
{
    int idx = blockIdx.x * 256 + threadIdx.x;
    if (idx >= M * Kp) return;
    int m = idx / Kp, k = idx % Kp;
    float v = (k < K) ? W[(size_t)k * M + m] : 0.0f;
    u16 h, l;
    splitbf(v, h, l);
    size_t o = tAddr(m & 127, k, m >> 7, Kp >> 5);
    bth[o] = h; btl[o] = l;
}

// ---------- split-bf16 MFMA GEMM, m97 staging structure ----------
// APLANES=0: A fp32 row-major (gemm1), staged via width-4 gload_lds with
//            source-address swizzle; split to hi/lo during frag read.
// APLANES=1: A pre-split tiled planes, staged via width-16 gload_lds linear copy.
// B always pre-split tiled planes. 128x128 tile, 4 waves, 16x16x32 bf16 MFMA x3.
#define BM 128
#define BN 128
template <int APLANES>
__global__ __launch_bounds__(256) void gemm_mfma(
    const float* __restrict__ Af, const u16* __restrict__ Aph, const u16* __restrict__ Apl,
    const u16* __restrict__ Bth, const u16* __restrict__ Btl,
    const float* __restrict__ bias, float* __restrict__ Cf,
    u16* __restrict__ Ch, u16* __restrict__ Cl,
    int N, int K, int Kp, int M, int dobias, int nktC)
{
    __shared__ __align__(16) char smem[32768];
    float (*sAf)[32] = reinterpret_cast<float(*)[32]>(smem);         // 16KB (APLANES==0)
    u16 (*sAh)[32] = reinterpret_cast<u16(*)[32]>(smem);             // 8KB (APLANES==1)
    u16 (*sAl)[32] = reinterpret_cast<u16(*)[32]>(smem + 8192);
    u16 (*sBh)[32] = reinterpret_cast<u16(*)[32]>(smem + 16384);
    u16 (*sBl)[32] = reinterpret_cast<u16(*)[32]>(smem + 24576);

    const int tid = threadIdx.x, lane = tid & 63, w = tid >> 6;
    const int wm = w >> 1, wn = w & 1;
    const int row0 = blockIdx.y * BM;
    const int nt = Kp >> 5;

    f32x4 acc[4][4];
    #pragma unroll
    for (int i = 0; i < 4; ++i)
        #pragma unroll
        for (int j = 0; j < 4; ++j)
            acc[i][j] = (f32x4)0.0f;

    for (int kt = 0; kt < nt; ++kt) {
        const int k0 = kt << 5;
        // ---- stage A (async) ----
        if constexpr (APLANES == 0) {
            #pragma unroll
            for (int j = 0; j < 16; ++j) {
                int slot = (w * 16 + j) * 64;        // uniform dword base
                int s = slot + lane;
                int r = s >> 5, cp = s & 31;
                int ch = (cp >> 2) ^ (r & 7);        // source-address swizzle
                int fi = cp & 3;
                int gr = row0 + r; if (gr >= N) gr = N - 1;
                int gk = k0 + (ch << 2) + fi; if (gk >= K) gk = K - 1;  // B zero-pad covers
                gl_lds4(Af + (size_t)gr * K + gk, smem + (size_t)s * 4);
            }
        } else {
            const char* gh = (const char*)(Aph + (((size_t)blockIdx.y * nt + kt) << 12));
            const char* gl = (const char*)(Apl + (((size_t)blockIdx.y * nt + kt) << 12));
            #pragma unroll
            for (int j = 0; j < 2; ++j) {
                int bo = (w * 2 + j) * 1024 + lane * 16;
                gl_lds16(gh + bo, smem + bo);
                gl_lds16(gl + bo, smem + 8192 + bo);
            }
        }
        // ---- stage B (async, linear copy of tiled image) ----
        {
            const char* gh = (const char*)(Bth + (((size_t)blockIdx.x * nt + kt) << 12));
            const char* gl = (const char*)(Btl + (((size_t)blockIdx.x * nt + kt) << 12));
            #pragma unroll
            for (int j = 0; j < 2; ++j) {
                int bo = (w * 2 + j) * 1024 + lane * 16;
                gl_lds16(gh + bo, smem + 16384 + bo);
                gl_lds16(gl + bo, smem + 24576 + bo);
            }
        }
        __syncthreads();   // compiler drains vmcnt before barrier

        // ---- frag read + MFMA ----
        const int g = lane >> 4;
        const int rA0 = wm * 64 + (lane & 15);
        const int rB0 = wn * 64 + (lane & 15);
        bf16x8 ah[4], al[4];
        if constexpr (APLANES == 0) {
            #pragma unroll
            for (int m = 0; m < 4; ++m) {
                int rr = rA0 + m * 16, x7 = rr & 7;
                float4 f0 = *reinterpret_cast<const float4*>(&sAf[rr][((2 * g) ^ x7) << 2]);
                float4 f1 = *reinterpret_cast<const float4*>(&sAf[rr][((2 * g + 1) ^ x7) << 2]);
                split8(f0, f1, ah[m], al[m]);
            }
        } else {
            #pragma unroll
            for (int m = 0; m < 4; ++m) {
                int rr = rA0 + m * 16;
                int cu = (g ^ ((rr >> 1) & 3)) << 3;
                ah[m] = *reinterpret_cast<const bf16x8*>(&sAh[rr][cu]);
                al[m] = *reinterpret_cast<const bf16x8*>(&sAl[rr][cu]);
            }
        }
        #pragma unroll
        for (int n = 0; n < 4; ++n) {
            int rr = rB0 + n * 16;
            int cu = (g ^ ((rr >> 1) & 3)) << 3;
            bf16x8 bh = *reinterpret_cast<const bf16x8*>(&sBh[rr][cu]);
            bf16x8 bl = *reinterpret_cast<const bf16x8*>(&sBl[rr][cu]);
            #pragma unroll
            for (int m = 0; m < 4; ++m) {
                acc[m][n] = __builtin_amdgcn_mfma_f32_16x16x32_bf16(ah[m], bh, acc[m][n], 0, 0, 0);
                acc[m][n] = __builtin_amdgcn_mfma_f32_16x16x32_bf16(al[m], bh, acc[m][n], 0, 0, 0);
                acc[m][n] = __builtin_amdgcn_mfma_f32_16x16x32_bf16(ah[m], bl, acc[m][n], 0, 0, 0);
            }
        }
        __syncthreads();
    }

    // ---- epilogue: D layout col=lane&15, row=(lane>>4)*4+reg ----
    #pragma unroll
    for (int m = 0; m < 4; ++m) {
        #pragma unroll
        for (int n = 0; n < 4; ++n) {
            int col = blockIdx.x * BN + wn * 64 + n * 16 + (lane & 15);
            #pragma unroll
            for (int r = 0; r < 4; ++r) {
                int row = row0 + wm * 64 + m * 16 + (lane >> 4) * 4 + r;
                if (row < N) {
                    float v = acc[m][n][r];
                    if (dobias) v = fmaxf(v + bias[col], 0.0f);
                    if (Cf) Cf[(size_t)row * M + col] = v;
                    if (Ch) {
                        u16 h, l;
                        splitbf(v, h, l);
                        size_t o = tAddr(row & 127, col, row >> 7, nktC);
                        Ch[o] = h; Cl[o] = l;
                    }
                }
            }
        }
    }
}

// ---------- per-node attention coefficients ----------
template <int F>
__global__ __launch_bounds__(256) void attn_coeff(
    const float* __restrict__ h, const float* __restrict__ att_src,
    const float* __restrict__ att_dst, float* __restrict__ a_src,
    float* __restrict__ a_dst, int N)
{
    constexpr int VPT = F / 64;
    constexpr int C = F / 4;
    int wave = (blockIdx.x * blockDim.x + threadIdx.x) >> 6;
    int lane = threadIdx.x & 63;
    if (wave >= N) return;
    int j0 = lane * VPT;
    int hd = j0 / C;
    float ps = 0.f, pd = 0.f;
    #pragma unroll
    for (int t = 0; t < VPT; ++t) {
        int j = j0 + t;
        float v = h[(size_t)wave * F + j];
        int c = j - hd * C;
        ps += v * att_src[hd * C + c];
        pd += v * att_dst[hd * C + c];
    }
    #pragma unroll
    for (int off = 8; off >= 1; off >>= 1) {
        ps += __shfl_xor(ps, off, 64);
        pd += __shfl_xor(pd, off, 64);
    }
    if ((lane & 15) == 0) {
        a_src[wave * 4 + hd] = ps;
        a_dst[wave * 4 + hd] = pd;
    }
}

// ---------- CSR build ----------
__global__ __launch_bounds__(256) void hist_kernel(
    const int* __restrict__ ei, int* __restrict__ counts, int E, int Etot)
{
    int i = blockIdx.x * blockDim.x + threadIdx.x;
    if (i >= Etot) return;
    int d = (i < E) ? ei[E + i] : (i - E);
    atomicAdd(&counts[d], 1);
}

__global__ __launch_bounds__(256) void scan1_kernel(
    const int* __restrict__ counts, int* __restrict__ row_ptr,
    int* __restrict__ partials, int N)
{
    __shared__ int sh[256];
    int tid = threadIdx.x;
    int i = blockIdx.x * 256 + tid;
    int v = (i < N) ? counts[i] : 0;
    sh[tid] = v;
    __syncthreads();
    #pragma unroll
    for (int off = 1; off < 256; off <<= 1) {
        int t = (tid >= off) ? sh[tid - off] : 0;
        __syncthreads();
        sh[tid] += t;
        __syncthreads();
    }
    if (i < N) row_ptr[i + 1] = sh[tid];
    if (tid == 255) partials[blockIdx.x] = sh[255];
}

__global__ __launch_bounds__(256) void scan2_kernel(int* __restrict__ partials, int nb)
{
    __shared__ int sh[256];
    int tid = threadIdx.x;
    int v = (tid < nb) ? partials[tid] : 0;
    sh[tid] = v;
    __syncthreads();
    #pragma unroll
    for (int off = 1; off < 256; off <<= 1) {
        int t = (tid >= off) ? sh[tid - off] : 0;
        __syncthreads();
        sh[tid] += t;
        __syncthreads();
    }
    if (tid < nb) partials[tid] = sh[tid] - v;
}

__global__ __launch_bounds__(256) void scan3_kernel(
    int* __restrict__ row_ptr, const int* __restrict__ partials, int N)
{
    int i = blockIdx.x * 256 + threadIdx.x;
    if (i == 0) row_ptr[0] = 0;
    if (i < N) row_ptr[i + 1] += partials[i >> 8];
}

__global__ __launch_bounds__(256) void fill_kernel(
    const int* __restrict__ ei, int* __restrict__ cursor,
    int* __restrict__ col, int E, int Etot)
{
    int i = blockIdx.x * blockDim.x + threadIdx.x;
    if (i >= Etot) return;
    int s, d;
    if (i < E) { s = ei[i]; d = ei[E + i]; } else { s = i - E; d = s; }
    int slot = atomicAdd(&cursor[d], 1);
    col[slot] = s;
}

// ---------- fused per-dst GAT aggregation ----------
// outF fp32 row-major, OR outH/outL tiled bf16 planes (nktP tiles) for next GEMM.
template <int F>
__global__ __launch_bounds__(256) void gat_aggregate(
    const int* __restrict__ row_ptr, const int* __restrict__ col,
    const float* __restrict__ h, const float* __restrict__ a_src,
    const float* __restrict__ a_dst, const float* __restrict__ bias,
    float* __restrict__ outF, u16* __restrict__ outH, u16* __restrict__ outL,
    int N, int nktP)
{
    constexpr int VPT = F / 64;
    int wave = (blockIdx.x * blockDim.x + threadIdx.x) >> 6;
    int lane = threadIdx.x & 63;
    if (wave >= N) return;
    const int d = wave;
    const int start = row_ptr[d], end = row_ptr[d + 1];

    float4 adv = *reinterpret_cast<const float4*>(&a_dst[d * 4]);
    const float ad[4] = {adv.x, adv.y, adv.z, adv.w};

    float m[4] = {-1e30f, -1e30f, -1e30f, -1e30f};
    for (int j = start + lane; j < end; j += 64) {
        int s = col[j];
        float4 asv = *reinterpret_cast<const float4*>(&a_src[s * 4]);
        float ev[4] = {asv.x + ad[0], asv.y + ad[1], asv.z + ad[2], asv.w + ad[3]};
        #pragma unroll
        for (int hd = 0; hd < 4; ++hd) {
            float e = ev[hd];
            e = (e >= 0.f) ? e : NEG_SLOPE * e;
            m[hd] = fmaxf(m[hd], e);
        }
    }
    #pragma unroll
    for (int off = 32; off >= 1; off >>= 1) {
        #pragma unroll
        for (int hd = 0; hd < 4; ++hd)
            m[hd] = fmaxf(m[hd], __shfl_xor(m[hd], off, 64));
    }

    float den[4] = {0.f, 0.f, 0.f, 0.f};
    for (int j = start + lane; j < end; j += 64) {
        int s = col[j];
        float4 asv = *reinterpret_cast<const float4*>(&a_src[s * 4]);
        float ev[4] = {asv.x + ad[0], asv.y + ad[1], asv.z + ad[2], asv.w + ad[3]};
        #pragma unroll
        for (int hd = 0; hd < 4; ++hd) {
            float e = ev[hd];
            e = (e >= 0.f) ? e : NEG_SLOPE * e;
            den[hd] += __expf(e - m[hd]);
        }
    }
    #pragma unroll
    for (int off = 32; off >= 1; off >>= 1) {
        #pragma unroll
        for (int hd = 0; hd < 4; ++hd)
            den[hd] += __shfl_xor(den[hd], off, 64);
    }

    const int hd_l = lane >> 4;
    const float mm = m[hd_l];
    const float iv = 1.0f / (den[hd_l] + 1e-16f);
    const float adh = ad[hd_l];
    float acc[VPT] = {};
    for (int j = start; j < end; ++j) {
        int s = col[j];
        float e = a_src[s * 4 + hd_l] + adh;
        e = (e >= 0.f) ? e : NEG_SLOPE * e;
        float alpha = __expf(e - mm) * iv;
        if constexpr (VPT == 4) {
            float4 hv = *reinterpret_cast<const float4*>(&h[(size_t)s * F + lane * 4]);
            acc[0] += hv.x * alpha; acc[1] += hv.y * alpha;
            acc[2] += hv.z * alpha; acc[3] += hv.w * alpha;
        } else {
            float2 hv = *reinterpret_cast<const float2*>(&h[(size_t)s * F + lane * 2]);
            acc[0] += hv.x * alpha; acc[1] += hv.y * alpha;
        }
    }
    #pragma unroll
    for (int t = 0; t < VPT; ++t) {
        int j = lane * VPT + t;
        float v = fmaxf(acc[t] + bias[j], 0.0f);
        if (outF) {
            outF[(size_t)d * F + j] = v;
        } else {
            u16 hh, ll;
            splitbf(v, hh, ll);
            size_t o = tAddr(d & 127, j, d >> 7, nktP);
            outH[o] = hh; outL[o] = ll;
        }
    }
}

// ---------- mean pool: batch SORTED -> register accumulate, flush on change ----------
#define POOL_RPW 64
__global__ __launch_bounds__(256) void pool_kernel(
    const float* __restrict__ h2, const int* __restrict__ batch,
    float* __restrict__ pooled, float* __restrict__ counts, int N)
{
    int wave = (blockIdx.x * blockDim.x + threadIdx.x) >> 6;
    int lane = threadIdx.x & 63;
    int r0 = wave * POOL_RPW;
    if (r0 >= N) return;
    int r1 = min(r0 + POOL_RPW, N);
    int cur_g = batch[r0];
    float a0 = 0.f, a1 = 0.f, cnt = 0.f;
    for (int r = r0; r < r1; ++r) {
        int g = batch[r];
        if (g != cur_g) {
            atomicAdd(&pooled[cur_g * 128 + lane * 2 + 0], a0);
            atomicAdd(&pooled[cur_g * 128 + lane * 2 + 1], a1);
            if (lane == 0) atomicAdd(&counts[cur_g], cnt);
            a0 = a1 = cnt = 0.f;
            cur_g = g;
        }
        float2 hv = *reinterpret_cast<const float2*>(&h2[(size_t)r * 128 + lane * 2]);
        a0 += hv.x; a1 += hv.y; cnt += 1.f;
    }
    atomicAdd(&pooled[cur_g * 128 + lane * 2 + 0], a0);
    atomicAdd(&pooled[cur_g * 128 + lane * 2 + 1], a1);
    if (lane == 0) atomicAdd(&counts[cur_g], cnt);
}

// ---------- classifier head ----------
__global__ __launch_bounds__(256) void head_kernel(
    const float* __restrict__ pooled, const float* __restrict__ counts,
    const float* __restrict__ Wc, const float* __restrict__ bc,
    const float* __restrict__ Wf, const float* __restrict__ bf,
    float* __restrict__ out)
{
    int wave = (blockIdx.x * blockDim.x + threadIdx.x) >> 6;
    int lane = threadIdx.x & 63;
    if (wave >= 64) return;
    float inv = 1.0f / fmaxf(counts[wave], 1.0f);
    float p0 = pooled[wave * 128 + lane] * inv;
    float p1 = pooled[wave * 128 + 64 + lane] * inv;
    float a0 = p0 * Wc[lane * 2 + 0] + p1 * Wc[(lane + 64) * 2 + 0];
    float a1 = p0 * Wc[lane * 2 + 1] + p1 * Wc[(lane + 64) * 2 + 1];
    float ac = p0 * Wf[lane] + p1 * Wf[lane + 64];
    #pragma unroll
    for (int off = 32; off >= 1; off >>= 1) {
        a0 += __shfl_xor(a0, off, 64);
        a1 += __shfl_xor(a1, off, 64);
        ac += __shfl_xor(ac, off, 64);
    }
    if (lane == 0) {
        out[wave * 2 + 0] = a0 + bc[0];
        out[wave * 2 + 1] = a1 + bc[1];
        out[128 + wave] = 1.0f / (1.0f + __expf(-(ac + bf[0])));
    }
}

extern "C" void kernel_launch(void* const* d_in, const int* in_sizes, int n_in,
                              void* d_out, int out_size, void* d_ws, size_t ws_size,
                              hipStream_t stream)
{
    const float* x     = (const float*)d_in[0];
    const int*   ei    = (const int*)d_in[1];
    const int*   batch = (const int*)d_in[2];
    const float* W_in  = (const float*)d_in[3];
    const float* b_in  = (const float*)d_in[4];
    const float* W1    = (const float*)d_in[5];
    const float* as1   = (const float*)d_in[6];
    const float* ad1   = (const float*)d_in[7];
    const float* bias1 = (const float*)d_in[8];
    const float* W2    = (const float*)d_in[9];
    const float* as2   = (const float*)d_in[10];
    const float* ad2   = (const float*)d_in[11];
    const float* bias2 = (const float*)d_in[12];
    const float* Wc    = (const float*)d_in[13];
    const float* bc    = (const float*)d_in[14];
    const float* Wf    = (const float*)d_in[15];
    const float* bf    = (const float*)d_in[16];
    float* out = (float*)d_out;

    const int N    = in_sizes[2];          // 50000
    const int E    = in_sizes[1] / 2;      // 800000
    const int K0   = in_sizes[0] / N;      // 773
    const int Etot = E + N;
    const int HID = 256, OUTF = 128;
    const int Kp0 = ((K0 + 31) / 32) * 32; // 800
    const int nb  = (N + 255) / 256;
    const int nrb = (N + BM - 1) / BM;     // 391 row blocks
    const int nktH = HID / 32;             // 8

    char* ws = (char*)d_ws;
    size_t off = 0;
    auto alloc = [&](size_t bytes) -> void* {
        void* p = ws + off;
        off = (off + bytes + 255) & ~(size_t)255;
        return p;
    };
    // tiled A planes (h0, later h1): nrb x nktH x 4096 elems per plane
    size_t planeElems = (size_t)nrb * nktH * 4096;
    u16* Ah = (u16*)alloc(planeElems * 2);
    u16* Al = (u16*)alloc(planeElems * 2);
    float* P1      = (float*)alloc((size_t)N * HID * 4);    // hc1 | hc2 + out2
    float* a_src   = (float*)alloc((size_t)N * 4 * 4);
    float* a_dst   = (float*)alloc((size_t)N * 4 * 4);
    int*   counts  = (int*)alloc((size_t)(N + 1) * 4);
    int*   row_ptr = (int*)alloc((size_t)(N + 1) * 4);
    int*   cursor  = (int*)alloc((size_t)N * 4);
    int*   colv    = (int*)alloc((size_t)Etot * 4);
    int*   partials= (int*)alloc(256 * 4);
    float* pooled  = (float*)alloc(64 * 128 * 4);
    float* gcounts = (float*)alloc(64 * 4);
    u16* Bth0 = (u16*)alloc((size_t)HID * Kp0 * 2);
    u16* Btl0 = (u16*)alloc((size_t)HID * Kp0 * 2);
    u16* Bth1 = (u16*)alloc((size_t)HID * HID * 2);
    u16* Btl1 = (u16*)alloc((size_t)HID * HID * 2);
    u16* Bth2 = (u16*)alloc((size_t)OUTF * HID * 2);
    u16* Btl2 = (u16*)alloc((size_t)OUTF * HID * 2);
    (void)ws_size; (void)n_in; (void)out_size;

    float* hc1  = P1;
    float* hc2  = P1;                               // reuse after agg1
    float* out2 = P1 + (size_t)N * OUTF;

    dim3 blk(256);
    dim3 gEdge((Etot + 255) / 256);
    dim3 gNodeWave((N + 3) / 4);
    dim3 gNodeTh((N + 255) / 256);
    dim3 gPool(((N + POOL_RPW - 1) / POOL_RPW + 3) / 4);

    // ---- weight split/transpose into tiled images (tiny) ----
    convertB<<<dim3((HID * Kp0 + 255) / 256), blk, 0, stream>>>(W_in, Bth0, Btl0, K0, HID, Kp0);
    convertB<<<dim3((HID * HID + 255) / 256), blk, 0, stream>>>(W1, Bth1, Btl1, HID, HID, HID);
    convertB<<<dim3((OUTF * HID + 255) / 256), blk, 0, stream>>>(W2, Bth2, Btl2, HID, OUTF, HID);

    // ---- CSR build (reused by both GAT layers) ----
    hipMemsetAsync(counts, 0, (size_t)(N + 1) * 4, stream);
    hist_kernel<<<gEdge, blk, 0, stream>>>(ei, counts, E, Etot);
    scan1_kernel<<<dim3(nb), blk, 0, stream>>>(counts, row_ptr, partials, N);
    scan2_kernel<<<dim3(1), blk, 0, stream>>>(partials, nb);
    scan3_kernel<<<gNodeTh, blk, 0, stream>>>(row_ptr, partials, N);
    hipMemcpyAsync(cursor, row_ptr, (size_t)N * 4, hipMemcpyDeviceToDevice, stream);
    fill_kernel<<<gEdge, blk, 0, stream>>>(ei, cursor, colv, E, Etot);

    // ---- input projection: h0 = relu(x @ W_in + b_in) -> tiled planes ----
    gemm_mfma<0><<<dim3(HID / BN, nrb), blk, 0, stream>>>(
        x, nullptr, nullptr, Bth0, Btl0, b_in, nullptr, Ah, Al,
        N, K0, Kp0, HID, 1, nktH);

    // ---- GAT conv 1: hc1 = h0 @ W1 ----
    gemm_mfma<1><<<dim3(HID / BN, nrb), blk, 0, stream>>>(
        nullptr, Ah, Al, Bth1, Btl1, nullptr, hc1, nullptr, nullptr,
        N, HID, HID, HID, 0, 0);
    attn_coeff<256><<<gNodeWave, blk, 0, stream>>>(hc1, as1, ad1, a_src, a_dst, N);
    gat_aggregate<256><<<gNodeWave, blk, 0, stream>>>(
        row_ptr, colv, hc1, a_src, a_dst, bias1, nullptr, Ah, Al, N, nktH);

    // ---- GAT conv 2: hc2 = h1 @ W2 ----
    gemm_mfma<1><<<dim3(OUTF / BN, nrb), blk, 0, stream>>>(
        nullptr, Ah, Al, Bth2, Btl2, nullptr, hc2, nullptr, nullptr,
        N, HID, HID, OUTF, 0, 0);
    attn_coeff<128><<<gNodeWave, blk, 0, stream>>>(hc2, as2, ad2, a_src, a_dst, N);
    gat_aggregate<128><<<gNodeWave, blk, 0, stream>>>(
        row_ptr, colv, hc2, a_src, a_dst, bias2, out2, nullptr, nullptr, N, 0);

    // ---- pool + head ----
    hipMemsetAsync(pooled, 0, 64 * 128 * 4 + 64 * 4, stream);
    pool_kernel<<<gPool, blk, 0, stream>>>(out2, batch, pooled, gcounts, N);
    head_kernel<<<dim3(16), blk, 0, stream>>>(pooled, gcounts, Wc, bc, Wf, bf, out);
}